// Round 8
// baseline (28738.016 us; speedup 1.0000x reference)
//
#include <hip/hip_runtime.h>
#include <hip/hip_bf16.h>

#define H      1024
#define IN_DIM 512
#define OD     512
#define T_LEN  16384
#define NWG    256    // 4 waves/WG: wave 0 = global reader, waves 1-3 = LDS consumers
#define NREP   16     // value-array replicas (readers/replica = 256/16 = 16)
#define RS     (H + 64)        // replica stride in floats (256B pad)
#define PSTRIDE (NREP * RS)    // parity stride in floats

typedef unsigned long long u64;
typedef unsigned int u32;

__device__ __forceinline__ u32 pack_bf(float lo, float hi) {
    u32 a = __float_as_uint(lo); a = (a + 0x7fffu + ((a >> 16) & 1u)) >> 16;          // RNE -> [15:0]
    u32 b = __float_as_uint(hi); b = (b + 0x7fffu + ((b >> 16) & 1u)) & 0xffff0000u;  // RNE -> [31:16]
    return a | b;
}
__device__ __forceinline__ float bf_lo(u32 pk) { return __uint_as_float(pk << 16); }
__device__ __forceinline__ float bf_hi(u32 pk) { return __uint_as_float(pk & 0xffff0000u); }

// vals[parity][rep][RS]: f32 h-state, mantissa LSB = lap bit ((tag>>1)&1).
// tag T == h after T steps (h_0 = 0). Consumer iter t expects lap (t>>1)&1 in
// parity t&1; producer of tag t+1 writes parity (t+1)&1 with lap ((t+1)>>1)&1.
// WG-shared ingest: wave 0 polls global (8 coalesced u64 agent loads = whole
// 4KB vector, lane l owns cols {2l,2l+1}+128k), then ds_writes the u64s to
// lsh[parity][k][lane]; waves 1-3 spin on LDS lap bits (no fabric traffic).
// Race-freedom (tag monotonicity): any publish of t+1 data-depends on that
// wave's ingest of t (global for wave 0, LDS for waves 1-3); overwrite of a
// parity slot (global or LDS) with t+2 requires all t+2... transitively all
// waves' publishes of t+1, hence all parity-t reads complete. Per-u64 lap
// check makes partially-written LDS/global state safe. LDS parity0 init = 0
// (= h_0 valid for t=0), parity1 init lap=1 (blocks t=1).
// x-prefetch issued AFTER detect (latency hides under compute, stays out of
// the spin's vmcnt drain); x-partials computed AFTER publish (pre-spin empty).
__global__ __launch_bounds__(256, 1)
void gru_rec_kernel(const float* __restrict__ X,
                    const float* __restrict__ Wih,
                    const float* __restrict__ Whh,
                    const float* __restrict__ bih,
                    const float* __restrict__ bhh,
                    float* __restrict__ hs,
                    u32* __restrict__ vals)
{
    __shared__ u64 lsh[2][8][64];   // 8 KB: [parity][k][lane]

    const int tid  = threadIdx.x;
    const int wave = tid >> 6;
    const int lane = tid & 63;
    const int wg   = blockIdx.x;
    const int gw   = wg * 4 + wave;        // global wave == hidden unit u
    const int u    = gw;

    // ---- weights -> registers, bf16-packed; lane l owns cols {2l,2l+1}+128k ----
    u32 whh_r[3][8];
    u32 wih_r[3][4];
    #pragma unroll
    for (int g = 0; g < 3; ++g) {
        const float* wr = Whh + (size_t)(g * H + u) * H;
        #pragma unroll
        for (int k = 0; k < 8; ++k)
            whh_r[g][k] = pack_bf(wr[2 * lane + 128 * k], wr[2 * lane + 1 + 128 * k]);
        const float* wx = Wih + (size_t)(g * H + u) * IN_DIM;
        #pragma unroll
        for (int k = 0; k < 4; ++k)
            wih_r[g][k] = pack_bf(wx[2 * lane + 128 * k], wx[2 * lane + 1 + 128 * k]);
    }
    const float bxr = bih[u], bxz = bih[H + u], bxn = bih[2 * H + u];
    const float bhr = bhh[u], bhz = bhh[H + u], bhn = bhh[2 * H + u];

    // ---- LDS init: parity0 = 0 (h_0, lap 0, valid for t=0); parity1 lap = 1 ----
    {
        u32* lp = (u32*)lsh;
        for (int i = tid; i < 2048; i += 256) lp[i] = (i < 1024) ? 0u : 1u;
    }
    __syncthreads();

    // ---- x row t=0 + its partials (prologue) ----
    float xw[8];
    #pragma unroll
    for (int k = 0; k < 4; ++k) {
        float2 vv = *(const float2*)(X + 2 * lane + 128 * k);
        xw[2 * k] = vv.x; xw[2 * k + 1] = vv.y;
    }
    float pxr = 0.f, pxz = 0.f, pxns = 0.f;
    {
        float xn = 0.f;
        #pragma unroll
        for (int k = 0; k < 4; ++k) {
            const float x0 = xw[2 * k], x1 = xw[2 * k + 1];
            pxr += bf_lo(wih_r[0][k]) * x0 + bf_hi(wih_r[0][k]) * x1;
            pxz += bf_lo(wih_r[1][k]) * x0 + bf_hi(wih_r[1][k]) * x1;
            xn  += bf_lo(wih_r[2][k]) * x0 + bf_hi(wih_r[2][k]) * x1;
        }
        #pragma unroll
        for (int s = 32; s; s >>= 1) xn += __shfl_xor(xn, s, 64);
        pxns = xn;
    }

    const int rep = wg & (NREP - 1);
    float hmine = 0.f;                     // this wave's own h_t[u], full precision

    #pragma unroll 1
    for (int t = 0; t < T_LEN; ++t) {
        const u32 lapexp = (u32)((t >> 1) & 1);
        const int p = t & 1;
        u64 v[8];

        if (wave == 0) {
            // ---- global spin: 8 coalesced u64 agent loads (detect == data) ----
            const u64* pb = (const u64*)(vals + (size_t)p * PSTRIDE
                                              + (size_t)rep * RS) + lane;
            for (;;) {
                #pragma unroll
                for (int k = 0; k < 8; ++k)
                    v[k] = __hip_atomic_load(pb + 64 * k, __ATOMIC_RELAXED,
                                             __HIP_MEMORY_SCOPE_AGENT);
                u32 bad = 0;
                #pragma unroll
                for (int k = 0; k < 8; ++k)
                    bad |= ((u32)v[k] ^ lapexp) | ((u32)(v[k] >> 32) ^ lapexp);
                if (!(bad & 1u)) break;
            }
            // distribute to the WG (per-u64 ds_write; laps make partial state safe)
            #pragma unroll
            for (int k = 0; k < 8; ++k)
                __hip_atomic_store(&lsh[p][k][lane], v[k], __ATOMIC_RELAXED,
                                   __HIP_MEMORY_SCOPE_WORKGROUP);
        } else {
            // ---- LDS spin: zero fabric traffic, ~150cy reaction ----
            for (;;) {
                u32 bad = 0;
                #pragma unroll
                for (int k = 0; k < 8; ++k) {
                    v[k] = __hip_atomic_load(&lsh[p][k][lane], __ATOMIC_RELAXED,
                                             __HIP_MEMORY_SCOPE_WORKGROUP);
                    bad |= ((u32)v[k] ^ lapexp) | ((u32)(v[k] >> 32) ^ lapexp);
                }
                if (!(bad & 1u)) break;
            }
        }

        // rotating coalesced store of PREVIOUS hs row (v = h_t = reference hs[t-1]);
        // assigned to a consumer wave so the reader stays lean
        if (t && wave == 1 && wg == ((t - 1) & 255)) {
            u64* dst = (u64*)(hs + (size_t)(t - 1) * H) + lane;
            #pragma unroll
            for (int k = 0; k < 8; ++k) dst[64 * k] = v[k];
        }

        // issue next-x loads now: latency hides under h-partials/butterfly/gates
        float xn2[8];
        {
            const int tn = (t + 1 < T_LEN) ? (t + 1) : t;
            const float* xp = X + (size_t)tn * IN_DIM;
            #pragma unroll
            for (int k = 0; k < 4; ++k) {
                float2 vv = *(const float2*)(xp + 2 * lane + 128 * k);
                xn2[2 * k] = vv.x; xn2[2 * k + 1] = vv.y;
            }
        }

        // ---- h partials (lane-local values; only sums cross lanes) ----
        float ar = pxr, az = pxz, anh = 0.f;
        #pragma unroll
        for (int k = 0; k < 8; ++k) {
            const float h0 = __uint_as_float((u32)v[k]);
            const float h1 = __uint_as_float((u32)(v[k] >> 32));
            ar  += bf_lo(whh_r[0][k]) * h0 + bf_hi(whh_r[0][k]) * h1;
            az  += bf_lo(whh_r[1][k]) * h0 + bf_hi(whh_r[1][k]) * h1;
            anh += bf_lo(whh_r[2][k]) * h0 + bf_hi(whh_r[2][k]) * h1;
        }
        #pragma unroll
        for (int s = 32; s; s >>= 1) {
            ar  += __shfl_xor(ar,  s, 64);
            az  += __shfl_xor(az,  s, 64);
            anh += __shfl_xor(anh, s, 64);
        }

        // ---- gates (all lanes redundantly) + one-instruction NREP publish ----
        const float r = 1.f / (1.f + __expf(-(ar + bxr + bhr)));
        const float z = 1.f / (1.f + __expf(-(az + bxz + bhz)));
        const float e2 = __expf(2.f * (pxns + bxn + r * (anh + bhn)));
        const float n = 1.f - 2.f / (e2 + 1.f);   // tanh
        const float hnew = (1.f - z) * n + z * hmine;
        const u32 lapw = (u32)(((t + 1) >> 1) & 1);
        const u32 bits = (__float_as_uint(hnew) & ~1u) | lapw;
        hmine = __uint_as_float(bits);
        if (lane < NREP)
            __hip_atomic_store(vals + (size_t)((t + 1) & 1) * PSTRIDE
                                    + (size_t)lane * RS + u,
                               bits, __ATOMIC_RELAXED, __HIP_MEMORY_SCOPE_AGENT);
        if (t == T_LEN - 1 && lane == 0)
            hs[(size_t)t * H + u] = hmine;   // final row: tag T_LEN never re-read

        // ---- epilogue: x partials for t+1 (off the chain; hidden by visibility) ----
        {
            float xr2 = 0.f, xz2 = 0.f, xn3 = 0.f;
            #pragma unroll
            for (int k = 0; k < 4; ++k) {
                const float x0 = xn2[2 * k], x1 = xn2[2 * k + 1];
                xr2 += bf_lo(wih_r[0][k]) * x0 + bf_hi(wih_r[0][k]) * x1;
                xz2 += bf_lo(wih_r[1][k]) * x0 + bf_hi(wih_r[1][k]) * x1;
                xn3 += bf_lo(wih_r[2][k]) * x0 + bf_hi(wih_r[2][k]) * x1;
            }
            #pragma unroll
            for (int s = 32; s; s >>= 1) xn3 += __shfl_xor(xn3, s, 64);
            pxr = xr2; pxz = xz2; pxns = xn3;
        }
    }
}

// out[m,n] = sum_k hs[m,k] * Wfc[n,k] + bfc[n]   (M=16384, N=512, K=1024)
#define BM 64
#define BN 64
#define BK 16
__global__ __launch_bounds__(256)
void fc_kernel(const float* __restrict__ A, const float* __restrict__ B,
               const float* __restrict__ bias, float* __restrict__ C)
{
    __shared__ float As[BK][BM + 4];
    __shared__ float Bs[BK][BN + 4];
    const int tid = threadIdx.x;
    const int m0 = blockIdx.y * BM, n0 = blockIdx.x * BN;
    const int tx = tid & 15, ty = tid >> 4;
    float acc[4][4] = {};
    const int r = tid >> 2, c = (tid & 3) << 2;
    for (int k0 = 0; k0 < H; k0 += BK) {
        float4 va = *(const float4*)(A + (size_t)(m0 + r) * H + (k0 + c));
        As[c + 0][r] = va.x; As[c + 1][r] = va.y; As[c + 2][r] = va.z; As[c + 3][r] = va.w;
        float4 vb = *(const float4*)(B + (size_t)(n0 + r) * H + (k0 + c));
        Bs[c + 0][r] = vb.x; Bs[c + 1][r] = vb.y; Bs[c + 2][r] = vb.z; Bs[c + 3][r] = vb.w;
        __syncthreads();
        #pragma unroll
        for (int kk = 0; kk < BK; ++kk) {
            float4 a4 = *(const float4*)&As[kk][ty * 4];
            float4 b4 = *(const float4*)&Bs[kk][tx * 4];
            const float av[4] = {a4.x, a4.y, a4.z, a4.w};
            const float bv[4] = {b4.x, b4.y, b4.z, b4.w};
            #pragma unroll
            for (int i = 0; i < 4; ++i)
                #pragma unroll
                for (int j = 0; j < 4; ++j)
                    acc[i][j] += av[i] * bv[j];
        }
        __syncthreads();
    }
    #pragma unroll
    for (int i = 0; i < 4; ++i) {
        const int m = m0 + ty * 4 + i;
        #pragma unroll
        for (int j = 0; j < 4; ++j) {
            const int n = n0 + tx * 4 + j;
            C[(size_t)m * OD + n] = acc[i][j] + bias[n];
        }
    }
}

extern "C" void kernel_launch(void* const* d_in, const int* in_sizes, int n_in,
                              void* d_out, int out_size, void* d_ws, size_t ws_size,
                              hipStream_t stream) {
    const float* X   = (const float*)d_in[0];
    const float* Wih = (const float*)d_in[1];
    const float* Whh = (const float*)d_in[2];
    const float* bih = (const float*)d_in[3];
    const float* bhh = (const float*)d_in[4];
    const float* Wfc = (const float*)d_in[5];
    const float* bfc = (const float*)d_in[6];
    float* out = (float*)d_out;

    float* hs  = (float*)d_ws;                                   // 64 MB
    u32*  vals = (u32*)((char*)d_ws + (size_t)T_LEN * H * 4);    // 2*PSTRIDE*4 ~ 139 KB

    // parity0: h_0 = 0.0, lap 0 (valid for t=0). parity1: 0x01 bytes -> lap 1
    // blocks t=1 consumers until the real h_1 arrives.
    hipMemsetAsync(vals, 0x00, (size_t)PSTRIDE * 4, stream);
    hipMemsetAsync(vals + PSTRIDE, 0x01, (size_t)PSTRIDE * 4, stream);

    void* args[] = { (void*)&X, (void*)&Wih, (void*)&Whh, (void*)&bih,
                     (void*)&bhh, (void*)&hs, (void*)&vals };
    hipError_t e = hipLaunchCooperativeKernel((const void*)gru_rec_kernel,
                                              dim3(NWG), dim3(256), args, 0, stream);
    if (e != hipSuccess) {
        gru_rec_kernel<<<dim3(NWG), dim3(256), 0, stream>>>(X, Wih, Whh, bih, bhh, hs, vals);
    }

    dim3 fgrid(OD / BN, T_LEN / BM);
    fc_kernel<<<fgrid, dim3(256), 0, stream>>>(hs, Wfc, bfc, out);
}